// Round 6
// baseline (361.729 us; speedup 1.0000x reference)
//
#include <hip/hip_runtime.h>

// ---- problem constants ----
#define D_DIM 1024
#define B_DIM 16
#define T_DIM 2048
#define M_TOT (B_DIM * T_DIM)   // 32768 rows
#define K_DIM 1024
#define LN_EPS 1e-5f
#define CHUNK 16
#define NCH (T_DIM / CHUNK)     // 128 chunks

typedef _Float16 half8 __attribute__((ext_vector_type(8)));
typedef float f32x4 __attribute__((ext_vector_type(4)));

// ---------------- fp32 -> fp16 conversion, 8 elems/thread ----------------
__global__ __launch_bounds__(256) void cvt_f32_f16(const float* __restrict__ in,
                                                   _Float16* __restrict__ out, int n8) {
    int i = blockIdx.x * blockDim.x + threadIdx.x;
    int stride = gridDim.x * blockDim.x;
    for (; i < n8; i += stride) {
        const float4* p = (const float4*)in + 2 * (size_t)i;
        float4 a = p[0], b = p[1];
        half8 h;
        h[0] = (_Float16)a.x; h[1] = (_Float16)a.y; h[2] = (_Float16)a.z; h[3] = (_Float16)a.w;
        h[4] = (_Float16)b.x; h[5] = (_Float16)b.y; h[6] = (_Float16)b.z; h[7] = (_Float16)b.w;
        ((half8*)out)[i] = h;
    }
}

// ---------------- fp32 [1024][1024] -> fp16 transpose (for W_vx^T) ----------------
__global__ __launch_bounds__(256) void transpose_cvt(const float* __restrict__ in,
                                                     _Float16* __restrict__ out) {
    __shared__ _Float16 t[32][33];
    int bx = blockIdx.x * 32, by = blockIdx.y * 32;
    int tx = threadIdx.x, ty = threadIdx.y;   // (32, 8)
#pragma unroll
    for (int j = 0; j < 4; ++j)
        t[ty + 8 * j][tx] = (_Float16)in[(size_t)(by + ty + 8 * j) * 1024 + bx + tx];
    __syncthreads();
#pragma unroll
    for (int j = 0; j < 4; ++j)
        out[(size_t)(bx + ty + 8 * j) * 1024 + by + tx] = t[tx][ty + 8 * j];
}

// ================= 256x256 8-phase fp16 MFMA GEMM (C = A * B^T) =================
// Register ds_reads pipelined one phase ahead. RACE FIX (r5->r6): next-tile
// ra0/rb0 reads moved AFTER the phase-3 barrier — vmcnt only covers this
// wave's own loads; the barrier is what makes other waves' staging visible.

__device__ __forceinline__ void gl_lds16(const _Float16* g, _Float16* l) {
    __builtin_amdgcn_global_load_lds(
        (const __attribute__((address_space(1))) unsigned int*)g,
        (__attribute__((address_space(3))) unsigned int*)l,
        16, 0, 0);
}

// Stage one half-tile (128 rows x 64 cols fp16 = 16 KiB) into LDS.
// Linear LDS dest + inverse-XOR'd global source chunk (rule #21: both-sides swizzle).
__device__ __forceinline__ void stage_half(const _Float16* __restrict__ G, int ld,
                                           int row0, int kt,
                                           _Float16* lds_base, int wid, int lane) {
#pragma unroll
    for (int j = 0; j < 2; ++j) {
        int c0 = j * 512 + wid * 64;        // wave-uniform chunk base
        int c  = c0 + lane;                 // this lane's chunk 0..1023
        int rl = c >> 3;                    // row within half-tile (8 chunks/row)
        int ch = (c & 7) ^ (rl & 7);        // swizzled source 16B-chunk
        gl_lds16(G + (size_t)(row0 + rl) * ld + kt + ch * 8,
                 lds_base + (size_t)c0 * 8);
    }
}

// Fragment read with the same XOR -> conflict-free ds_read_b128 (verified: 0 conflicts).
__device__ __forceinline__ half8 frag_ld(const _Float16* base, int row, int ksub, int kq) {
    int ch = ((ksub << 2) | kq) ^ (row & 7);
    return *(const half8*)(base + (size_t)row * 64 + ch * 8);
}

// mode 0: out0[m*N + n] = (half)acc
// mode 1: n < D -> out0[m*D + n] = (half)sigmoid(acc) ; n >= D -> out1[m*D + n-D] = (half)acc
__global__ __launch_bounds__(512, 2) void gemm256(const _Float16* __restrict__ A,
                                                  const _Float16* __restrict__ Bm,
                                                  int Mtiles, int N, int K,
                                                  _Float16* __restrict__ out0,
                                                  _Float16* __restrict__ out1,
                                                  int mode) {
    __shared__ _Float16 As[2][256][64];
    __shared__ _Float16 Bs[2][256][64];

    int nwg = gridDim.x;
    int bid = blockIdx.x;
    int cpx = nwg >> 3;
    int lin = (bid & 7) * cpx + (bid >> 3);
    int nt = lin / Mtiles, mt = lin % Mtiles;
    int m0 = mt * 256, n0 = nt * 256;

    int tid = threadIdx.x, wid = tid >> 6, lane = tid & 63;
    int wr = wid >> 2, wc = wid & 3;         // 2 x 4 wave grid
    int r = lane & 15, kq = lane >> 4;

    f32x4 acc[8][4];
#pragma unroll
    for (int i = 0; i < 8; i++)
#pragma unroll
        for (int j = 0; j < 4; j++) acc[i][j] = (f32x4)0.f;

    const int nkt = K >> 6;                  // 16 K-tiles

    half8 ra0[4], ra1[4], ra2[4], ra3[4], rb0[4], rb1[4];

    // ---- prologue: stage tile0 fully + tile1.B1; vmcnt -> barrier -> read ----
    stage_half(Bm, K, n0 + 0,   0,  &Bs[0][0][0],   wid, lane);  // t0.B1
    stage_half(Bm, K, n0 + 128, 0,  &Bs[0][128][0], wid, lane);  // t0.B2
    stage_half(A,  K, m0 + 0,   0,  &As[0][0][0],   wid, lane);  // t0.A1
    stage_half(A,  K, m0 + 128, 0,  &As[0][128][0], wid, lane);  // t0.A2
    if (nkt > 1) {
        stage_half(Bm, K, n0 + 0, 64, &Bs[1][0][0], wid, lane);  // t1.B1
        asm volatile("s_waitcnt vmcnt(2)" ::: "memory");         // own t0 loads landed
    } else {
        asm volatile("s_waitcnt vmcnt(0)" ::: "memory");
    }
    __builtin_amdgcn_s_barrier();                                // all waves' t0 landed
#pragma unroll
    for (int mi = 0; mi < 4; mi++) ra0[mi] = frag_ld(&As[0][0][0], wr * 128 + mi * 16 + r, 0, kq);
#pragma unroll
    for (int ni = 0; ni < 4; ni++) rb0[ni] = frag_ld(&Bs[0][0][0], wc * 64 + ni * 16 + r, 0, kq);

    for (int t = 0; t < nkt; ++t) {
        const _Float16* Ac = &As[t & 1][0][0];
        const _Float16* Bc = &Bs[t & 1][0][0];
        int nb = (t & 1) ^ 1;
        int kt1 = (t + 1) << 6, kt2 = (t + 2) << 6;

        // ---- phase 0: MFMA G0 = ra0 x rb0 ; prefetch ra1 (for G1) ----
#pragma unroll
        for (int mi = 0; mi < 4; mi++) ra1[mi] = frag_ld(Ac, wr * 128 + 64 + mi * 16 + r, 0, kq);
        if (t + 1 < nkt) stage_half(Bm, K, n0 + 128, kt1, &Bs[nb][128][0], wid, lane); // (t+1).B2
        __builtin_amdgcn_s_barrier();
        __builtin_amdgcn_s_setprio(1);
#pragma unroll
        for (int mi = 0; mi < 4; mi++)
#pragma unroll
            for (int ni = 0; ni < 4; ni++)
                acc[mi][ni] = __builtin_amdgcn_mfma_f32_16x16x32_f16(ra0[mi], rb0[ni], acc[mi][ni], 0, 0, 0);
        __builtin_amdgcn_s_setprio(0);
        __builtin_amdgcn_s_barrier();

        // ---- phase 1: MFMA G1 = ra1 x rb0 ; prefetch ra2, rb1 (for G2) ----
#pragma unroll
        for (int mi = 0; mi < 4; mi++) ra2[mi] = frag_ld(Ac, wr * 128 + mi * 16 + r, 1, kq);
#pragma unroll
        for (int ni = 0; ni < 4; ni++) rb1[ni] = frag_ld(Bc, wc * 64 + ni * 16 + r, 1, kq);
        if (t + 1 < nkt) stage_half(A, K, m0 + 0, kt1, &As[nb][0][0], wid, lane);      // (t+1).A1
        __builtin_amdgcn_s_barrier();
        __builtin_amdgcn_s_setprio(1);
#pragma unroll
        for (int mi = 0; mi < 4; mi++)
#pragma unroll
            for (int ni = 0; ni < 4; ni++)
                acc[4 + mi][ni] = __builtin_amdgcn_mfma_f32_16x16x32_f16(ra1[mi], rb0[ni], acc[4 + mi][ni], 0, 0, 0);
        __builtin_amdgcn_s_setprio(0);
        __builtin_amdgcn_s_barrier();

        // ---- phase 2: MFMA G2 = ra2 x rb1 ; prefetch ra3 (for G3) ----
#pragma unroll
        for (int mi = 0; mi < 4; mi++) ra3[mi] = frag_ld(Ac, wr * 128 + 64 + mi * 16 + r, 1, kq);
        if (t + 1 < nkt) stage_half(A, K, m0 + 128, kt1, &As[nb][128][0], wid, lane);  // (t+1).A2
        __builtin_amdgcn_s_barrier();
        __builtin_amdgcn_s_setprio(1);
#pragma unroll
        for (int mi = 0; mi < 4; mi++)
#pragma unroll
            for (int ni = 0; ni < 4; ni++)
                acc[mi][ni] = __builtin_amdgcn_mfma_f32_16x16x32_f16(ra2[mi], rb1[ni], acc[mi][ni], 0, 0, 0);
        __builtin_amdgcn_s_setprio(0);
        __builtin_amdgcn_s_barrier();

        // ---- phase 3: stage (t+2).B1 ; own-vmcnt ; BARRIER ; then read next
        //      tile's ra0/rb0 (safe: all waves' (t+1) loads landed) ; MFMA G3 ----
        if (t + 2 < nkt) stage_half(Bm, K, n0 + 0, kt2, &Bs[t & 1][0][0], wid, lane);  // (t+2).B1
        if (t + 2 < nkt) {
            asm volatile("s_waitcnt vmcnt(2)" ::: "memory");   // own (t+1) loads landed
        } else if (t + 1 < nkt) {
            asm volatile("s_waitcnt vmcnt(0)" ::: "memory");
        }
        __builtin_amdgcn_s_barrier();                          // collective: (t+1) visible
        if (t + 1 < nkt) {
            const _Float16* An = &As[nb][0][0];
            const _Float16* Bn = &Bs[nb][0][0];
#pragma unroll
            for (int mi = 0; mi < 4; mi++) ra0[mi] = frag_ld(An, wr * 128 + mi * 16 + r, 0, kq);
#pragma unroll
            for (int ni = 0; ni < 4; ni++) rb0[ni] = frag_ld(Bn, wc * 64 + ni * 16 + r, 0, kq);
        }
        __builtin_amdgcn_s_setprio(1);
#pragma unroll
        for (int mi = 0; mi < 4; mi++)
#pragma unroll
            for (int ni = 0; ni < 4; ni++)
                acc[4 + mi][ni] = __builtin_amdgcn_mfma_f32_16x16x32_f16(ra3[mi], rb1[ni], acc[4 + mi][ni], 0, 0, 0);
        __builtin_amdgcn_s_setprio(0);
        __builtin_amdgcn_s_barrier();
    }

    // ---- epilogue: C/D layout col = lane&15, row = (lane>>4)*4 + q ----
    int rr = kq * 4;
#pragma unroll
    for (int mi = 0; mi < 8; mi++) {
        int mbase = m0 + wr * 128 + mi * 16 + rr;
#pragma unroll
        for (int ni = 0; ni < 4; ni++) {
            int n = n0 + wc * 64 + ni * 16 + r;
#pragma unroll
            for (int q = 0; q < 4; q++) {
                float v = acc[mi][ni][q];
                size_t m = (size_t)(mbase + q);
                if (mode == 1) {
                    if (n < D_DIM)
                        out0[m * D_DIM + n] = (_Float16)(1.f / (1.f + __expf(-v)));
                    else
                        out1[m * D_DIM + (n - D_DIM)] = (_Float16)v;
                } else {
                    out0[m * (size_t)N + n] = (_Float16)v;
                }
            }
        }
    }
}

// ---------------- chunked affine scan, pass 1 (CHUNK=16) ----------------
__global__ __launch_bounds__(256) void scan_pass1(const _Float16* __restrict__ u,
                                                  const _Float16* __restrict__ cd,
                                                  float* __restrict__ Ac, float* __restrict__ Bc) {
    int idx = blockIdx.x * 256 + threadIdx.x;   // (b*NCH + ch)*128 + dg
    int dg = idx & 127, bc = idx >> 7;
    int b = bc >> 7, ch = bc & (NCH - 1);
    int d0 = dg * 8;
    size_t base = ((size_t)b * T_DIM + (size_t)ch * CHUNK) * D_DIM + d0;
    float Aa[8], Bb[8];
#pragma unroll
    for (int j = 0; j < 8; ++j) { Aa[j] = 1.f; Bb[j] = 0.f; }
#pragma unroll
    for (int t = 0; t < CHUNK; ++t) {
        half8 u8 = *(const half8*)&u[base + (size_t)t * D_DIM];
        half8 c8 = *(const half8*)&cd[base + (size_t)t * D_DIM];
#pragma unroll
        for (int j = 0; j < 8; ++j) {
            float ut = (float)u8[j], ct = (float)c8[j];
            Aa[j] *= ut;
            Bb[j] = fmaf(ut, Bb[j], (1.f - ut) * ct);
        }
    }
    size_t o = (size_t)bc * D_DIM + d0;
    *(float4*)&Ac[o]     = *(float4*)&Aa[0];
    *(float4*)&Ac[o + 4] = *(float4*)&Aa[4];
    *(float4*)&Bc[o]     = *(float4*)&Bb[0];
    *(float4*)&Bc[o + 4] = *(float4*)&Bb[4];
}

// pass 2: sequential over chunks; AcH0 doubles as h0 output (read-before-write)
__global__ __launch_bounds__(256) void scan_pass2(float* __restrict__ AcH0,
                                                  const float* __restrict__ Bc) {
    int idx = blockIdx.x * 256 + threadIdx.x;   // b*D + d, 16384 total
    int b = idx >> 10, d = idx & (D_DIM - 1);
    float h = 0.f;
#pragma unroll 8
    for (int ch = 0; ch < NCH; ++ch) {
        size_t k = ((size_t)(b * NCH + ch) << 10) + d;
        float a = AcH0[k];
        float bv = Bc[k];
        AcH0[k] = h;
        h = fmaf(a, h, bv);
    }
}

// ---------------- fused scan pass 3 + LayerNorm (1 wave, 16 dims/lane) ----------------
__global__ __launch_bounds__(64) void scan_ln(const _Float16* __restrict__ u,
                                              const _Float16* __restrict__ cd,
                                              const float* __restrict__ h0,
                                              const float* __restrict__ gamma,
                                              const float* __restrict__ beta,
                                              float* __restrict__ outp) {
    int bc = blockIdx.x;                // b*NCH + ch
    int b = bc >> 7, ch = bc & (NCH - 1);
    int lane = threadIdx.x;             // 0..63
    int d0 = lane * 16;
    size_t base = ((size_t)b * T_DIM + (size_t)ch * CHUNK) * D_DIM + d0;

    float g[16], be[16], h[16];
#pragma unroll
    for (int j = 0; j < 16; j += 4) {
        *(float4*)&g[j]  = *(const float4*)&gamma[d0 + j];
        *(float4*)&be[j] = *(const float4*)&beta[d0 + j];
    }
    size_t o = (size_t)bc * D_DIM + d0;
#pragma unroll
    for (int j = 0; j < 16; j += 4) *(float4*)&h[j] = *(const float4*)&h0[o + j];

    for (int t = 0; t < CHUNK; ++t) {
        size_t row = base + (size_t)t * D_DIM;
        half8 ua = *(const half8*)&u[row];
        half8 ub = *(const half8*)&u[row + 8];
        half8 ca = *(const half8*)&cd[row];
        half8 cb = *(const half8*)&cd[row + 8];
        float s = 0.f, q = 0.f;
#pragma unroll
        for (int j = 0; j < 8; ++j) {
            float ut = (float)ua[j], ct = (float)ca[j];
            h[j] = fmaf(ut, h[j] - ct, ct);
            s += h[j]; q += h[j] * h[j];
        }
#pragma unroll
        for (int j = 0; j < 8; ++j) {
            float ut = (float)ub[j], ct = (float)cb[j];
            h[8 + j] = fmaf(ut, h[8 + j] - ct, ct);
            s += h[8 + j]; q += h[8 + j] * h[8 + j];
        }
#pragma unroll
        for (int off = 32; off > 0; off >>= 1) {
            s += __shfl_xor(s, off);
            q += __shfl_xor(q, off);
        }
        float mu = s * (1.f / D_DIM);
        float var = q * (1.f / D_DIM) - mu * mu;
        float rs = rsqrtf(var + LN_EPS);
        float o16[16];
#pragma unroll
        for (int j = 0; j < 16; ++j) o16[j] = (h[j] - mu) * rs * g[j] + be[j];
#pragma unroll
        for (int j = 0; j < 16; j += 4) *(float4*)&outp[row + j] = *(float4*)&o16[j];
    }
}

extern "C" void kernel_launch(void* const* d_in, const int* in_sizes, int n_in,
                              void* d_out, int out_size, void* d_ws, size_t ws_size,
                              hipStream_t stream) {
    const float* x       = (const float*)d_in[0];
    const float* W_in    = (const float*)d_in[1];
    const float* W_state = (const float*)d_in[2];
    const float* gamma   = (const float*)d_in[3];
    const float* beta    = (const float*)d_in[4];
    float* out = (float*)d_out;

    char* w = (char*)d_ws;
    size_t off = 0;
    auto carve = [&](size_t bytes) {
        void* p = w + off;
        off += (bytes + 255) & ~(size_t)255;
        return p;
    };
    _Float16* xh   = (_Float16*)carve((size_t)M_TOT * K_DIM * 2);           // 64 MiB
    _Float16* Wall = (_Float16*)carve((size_t)2 * D_DIM * K_DIM * 2);       // 4 MiB (W_g ; W_comb)
    _Float16* uarr = (_Float16*)carve((size_t)M_TOT * D_DIM * 2);           // 64 MiB
    _Float16* cand = (_Float16*)carve((size_t)M_TOT * D_DIM * 2);           // 64 MiB
    char* scratch  = (char*)carve((size_t)16 * 1024 * 1024);                // 16 MiB shared region
    _Float16* wvxT = (_Float16*)scratch;                                    // 2 MiB (early)
    _Float16* wst  = (_Float16*)(scratch + 2 * 1024 * 1024);                // 2 MiB (early)
    float* Ac = (float*)scratch;                                            // 8 MiB (late, also h0)
    float* Bc = (float*)(scratch + 8 * 1024 * 1024);                        // 8 MiB (late)

    // 1. casts
    cvt_f32_f16<<<2048, 256, 0, stream>>>(x, xh, M_TOT * K_DIM / 8);
    cvt_f32_f16<<<512, 256, 0, stream>>>(W_in, Wall, D_DIM * K_DIM / 8);
    transpose_cvt<<<dim3(32, 32), dim3(32, 8), 0, stream>>>(W_in + (size_t)D_DIM * K_DIM, wvxT);
    cvt_f32_f16<<<512, 256, 0, stream>>>(W_state, wst, D_DIM * K_DIM / 8);

    // 2. W_comb = W_state @ W_vx -> Wall[1024:2048]
    gemm256<<<16, 512, 0, stream>>>(wst, wvxT, 4, D_DIM, K_DIM,
                                    Wall + (size_t)D_DIM * K_DIM, nullptr, 0);

    // 3. fused projection: [u | cand] = x @ Wall^T  (sigmoid on u half)
    gemm256<<<(M_TOT / 256) * (2 * D_DIM / 256), 512, 0, stream>>>(
        xh, Wall, M_TOT / 256, 2 * D_DIM, K_DIM, uarr, cand, 1);

    // 4. chunked affine scan + fused LN
    scan_pass1<<<(B_DIM * NCH * 128) / 256, 256, 0, stream>>>(uarr, cand, Ac, Bc);
    scan_pass2<<<(B_DIM * D_DIM) / 256, 256, 0, stream>>>(Ac, Bc);
    scan_ln<<<B_DIM * NCH, 64, 0, stream>>>(uarr, cand, Ac, gamma, beta, out);
}

// Round 7
// 355.923 us; speedup vs baseline: 1.0163x; 1.0163x over previous
//
#include <hip/hip_runtime.h>

// ---- problem constants ----
#define D_DIM 1024
#define B_DIM 16
#define T_DIM 2048
#define M_TOT (B_DIM * T_DIM)   // 32768 rows
#define K_DIM 1024
#define LN_EPS 1e-5f
#define CHUNK 16
#define NCH (T_DIM / CHUNK)     // 128 chunks

typedef _Float16 half8 __attribute__((ext_vector_type(8)));
typedef float f32x4 __attribute__((ext_vector_type(4)));

// ---------------- fp32 -> fp16 conversion, 8 elems/thread ----------------
__global__ __launch_bounds__(256) void cvt_f32_f16(const float* __restrict__ in,
                                                   _Float16* __restrict__ out, int n8) {
    int i = blockIdx.x * blockDim.x + threadIdx.x;
    int stride = gridDim.x * blockDim.x;
    for (; i < n8; i += stride) {
        const float4* p = (const float4*)in + 2 * (size_t)i;
        float4 a = p[0], b = p[1];
        half8 h;
        h[0] = (_Float16)a.x; h[1] = (_Float16)a.y; h[2] = (_Float16)a.z; h[3] = (_Float16)a.w;
        h[4] = (_Float16)b.x; h[5] = (_Float16)b.y; h[6] = (_Float16)b.z; h[7] = (_Float16)b.w;
        ((half8*)out)[i] = h;
    }
}

// ---------------- fp32 [1024][1024] -> fp16 transpose (for W_vx^T) ----------------
__global__ __launch_bounds__(256) void transpose_cvt(const float* __restrict__ in,
                                                     _Float16* __restrict__ out) {
    __shared__ _Float16 t[32][33];
    int bx = blockIdx.x * 32, by = blockIdx.y * 32;
    int tx = threadIdx.x, ty = threadIdx.y;   // (32, 8)
#pragma unroll
    for (int j = 0; j < 4; ++j)
        t[ty + 8 * j][tx] = (_Float16)in[(size_t)(by + ty + 8 * j) * 1024 + bx + tx];
    __syncthreads();
#pragma unroll
    for (int j = 0; j < 4; ++j)
        out[(size_t)(bx + ty + 8 * j) * 1024 + by + tx] = t[tx][ty + 8 * j];
}

// ========== 256x256 quad-buffered BK=32 fp16 MFMA GEMM (C = A * B^T) ==========
// Deep pipeline (T4): tile t staged during tile t-3 -> issue-to-wait ~3 tiles
// (>HBM latency). Per tile: vmcnt(8) ; barrier ; stage(t+3).A ; 12x ds_read_b128 ;
// stage(t+3).B ; 32 MFMA ; barrier.  2 barriers / 32-K (half of prior rate).
// Buffer safety: a buffer's reads are consumed (lgkmcnt) before its tile-end
// barrier; restaging issues only after the NEXT tile-start barrier.

__device__ __forceinline__ void gl_lds16(const _Float16* g, _Float16* l) {
    __builtin_amdgcn_global_load_lds(
        (const __attribute__((address_space(1))) unsigned int*)g,
        (__attribute__((address_space(3))) unsigned int*)l,
        16, 0, 0);
}

// Stage a full 256x32 fp16 tile (16 KiB, 1024 16B-chunks) = 2 gl_lds / thread.
// Linear LDS dest + inverse-XOR'd global source chunk (both-sides swizzle).
__device__ __forceinline__ void stage32(const _Float16* __restrict__ G, int ld,
                                        int row0, int kt,
                                        _Float16* lds0, int wid, int lane) {
#pragma unroll
    for (int call = 0; call < 2; ++call) {
        int c0 = call * 512 + wid * 64;     // wave-uniform chunk base
        int c  = c0 + lane;                 // chunk 0..1023
        int rl = c >> 2;                    // row 0..255 (4 chunks/row)
        int cc = c & 3;
        int src = cc ^ ((rl >> 1) & 3);     // swizzled source chunk
        gl_lds16(G + (size_t)(row0 + rl) * ld + kt + src * 8,
                 lds0 + (size_t)c0 * 8);
    }
}

// Fragment read with matching XOR: 16 lanes spread 2-way over all 32 banks (free).
__device__ __forceinline__ half8 frag32(const _Float16* base, int row, int kq) {
    int cc = kq ^ ((row >> 1) & 3);
    return *(const half8*)(base + (size_t)row * 32 + cc * 8);
}

// mode 0: out0[m*N + n] = (half)acc
// mode 1: n < D -> out0[m*D + n] = (half)sigmoid(acc) ; n >= D -> out1[m*D + n-D] = (half)acc
__global__ __launch_bounds__(512, 2) void gemm256(const _Float16* __restrict__ A,
                                                  const _Float16* __restrict__ Bm,
                                                  int Mtiles, int N, int K,
                                                  _Float16* __restrict__ out0,
                                                  _Float16* __restrict__ out1,
                                                  int mode) {
    __shared__ _Float16 As[4][256][32];   // 64 KiB
    __shared__ _Float16 Bs[4][256][32];   // 64 KiB

    int bid = blockIdx.x;
    int mt, nt;
    if (Mtiles == 128) {
        // 2-D XCD supertile: each XCD owns 16 mt x 8 nt (shares A panels + B panels)
        int xcd = bid & 7;
        mt = xcd * 16 + ((bid >> 3) & 15);
        nt = bid >> 7;
    } else {
        int cpx = gridDim.x >> 3;
        int lin = (bid & 7) * cpx + (bid >> 3);
        nt = lin / Mtiles; mt = lin % Mtiles;
    }
    int m0 = mt * 256, n0 = nt * 256;

    int tid = threadIdx.x, wid = tid >> 6, lane = tid & 63;
    int wr = wid >> 2, wc = wid & 3;         // 2 x 4 wave grid, per-wave 128x64
    int r = lane & 15, kq = lane >> 4;       // kq = 16B chunk within BK=32 row

    f32x4 acc[8][4];
#pragma unroll
    for (int i = 0; i < 8; i++)
#pragma unroll
        for (int j = 0; j < 4; j++) acc[i][j] = (f32x4)0.f;

    const int nkt = K >> 5;                  // 32 K-tiles of BK=32

    // ---- prologue: stage tiles 0,1,2 (12 gl_lds/thread outstanding) ----
    stage32(A,  K, m0, 0,      &As[0][0][0], wid, lane);
    stage32(Bm, K, n0, 0,      &Bs[0][0][0], wid, lane);
    stage32(A,  K, m0, 32,     &As[1][0][0], wid, lane);
    stage32(Bm, K, n0, 32,     &Bs[1][0][0], wid, lane);
    stage32(A,  K, m0, 64,     &As[2][0][0], wid, lane);
    stage32(Bm, K, n0, 64,     &Bs[2][0][0], wid, lane);

    for (int t = 0; t < nkt; ++t) {
        const _Float16* Ab = &As[t & 3][0][0];
        const _Float16* Bb = &Bs[t & 3][0][0];
        int rem = nkt - 1 - t;
        // own-wave drain: tile t's 4 loads landed; leave t+1,t+2 (8) in flight
        if (rem >= 2)      asm volatile("s_waitcnt vmcnt(8)" ::: "memory");
        else if (rem == 1) asm volatile("s_waitcnt vmcnt(4)" ::: "memory");
        else               asm volatile("s_waitcnt vmcnt(0)" ::: "memory");
        __builtin_amdgcn_s_barrier();        // all waves' tile-t loads visible

        int kt3 = (t + 3) << 5;
        if (t + 3 < nkt) stage32(A, K, m0, kt3, &As[(t + 3) & 3][0][0], wid, lane);

        half8 rb[4], ra0[4], ra1[4];
#pragma unroll
        for (int ni = 0; ni < 4; ni++) rb[ni]  = frag32(Bb, wc * 64 + ni * 16 + r, kq);
#pragma unroll
        for (int mi = 0; mi < 4; mi++) ra0[mi] = frag32(Ab, wr * 128 + mi * 16 + r, kq);
#pragma unroll
        for (int mi = 0; mi < 4; mi++) ra1[mi] = frag32(Ab, wr * 128 + 64 + mi * 16 + r, kq);

        if (t + 3 < nkt) stage32(Bm, K, n0, kt3, &Bs[(t + 3) & 3][0][0], wid, lane);

        __builtin_amdgcn_s_setprio(1);
#pragma unroll
        for (int mi = 0; mi < 4; mi++)
#pragma unroll
            for (int ni = 0; ni < 4; ni++)
                acc[mi][ni] = __builtin_amdgcn_mfma_f32_16x16x32_f16(ra0[mi], rb[ni], acc[mi][ni], 0, 0, 0);
#pragma unroll
        for (int mi = 0; mi < 4; mi++)
#pragma unroll
            for (int ni = 0; ni < 4; ni++)
                acc[4 + mi][ni] = __builtin_amdgcn_mfma_f32_16x16x32_f16(ra1[mi], rb[ni], acc[4 + mi][ni], 0, 0, 0);
        __builtin_amdgcn_s_setprio(0);
        __builtin_amdgcn_s_barrier();        // reads consumed; buffer reusable
    }

    // ---- epilogue: C/D layout col = lane&15, row = (lane>>4)*4 + q ----
    int rr = kq * 4;
#pragma unroll
    for (int mi = 0; mi < 8; mi++) {
        int mbase = m0 + wr * 128 + mi * 16 + rr;
#pragma unroll
        for (int ni = 0; ni < 4; ni++) {
            int n = n0 + wc * 64 + ni * 16 + r;
#pragma unroll
            for (int q = 0; q < 4; q++) {
                float v = acc[mi][ni][q];
                size_t m = (size_t)(mbase + q);
                if (mode == 1) {
                    if (n < D_DIM)
                        out0[m * D_DIM + n] = (_Float16)(1.f / (1.f + __expf(-v)));
                    else
                        out1[m * D_DIM + (n - D_DIM)] = (_Float16)v;
                } else {
                    out0[m * (size_t)N + n] = (_Float16)v;
                }
            }
        }
    }
}

// ---------------- chunked affine scan, pass 1 (CHUNK=16) ----------------
__global__ __launch_bounds__(256) void scan_pass1(const _Float16* __restrict__ u,
                                                  const _Float16* __restrict__ cd,
                                                  float* __restrict__ Ac, float* __restrict__ Bc) {
    int idx = blockIdx.x * 256 + threadIdx.x;   // (b*NCH + ch)*128 + dg
    int dg = idx & 127, bc = idx >> 7;
    int b = bc >> 7, ch = bc & (NCH - 1);
    int d0 = dg * 8;
    size_t base = ((size_t)b * T_DIM + (size_t)ch * CHUNK) * D_DIM + d0;
    float Aa[8], Bb[8];
#pragma unroll
    for (int j = 0; j < 8; ++j) { Aa[j] = 1.f; Bb[j] = 0.f; }
#pragma unroll
    for (int t = 0; t < CHUNK; ++t) {
        half8 u8 = *(const half8*)&u[base + (size_t)t * D_DIM];
        half8 c8 = *(const half8*)&cd[base + (size_t)t * D_DIM];
#pragma unroll
        for (int j = 0; j < 8; ++j) {
            float ut = (float)u8[j], ct = (float)c8[j];
            Aa[j] *= ut;
            Bb[j] = fmaf(ut, Bb[j], (1.f - ut) * ct);
        }
    }
    size_t o = (size_t)bc * D_DIM + d0;
    *(float4*)&Ac[o]     = *(float4*)&Aa[0];
    *(float4*)&Ac[o + 4] = *(float4*)&Aa[4];
    *(float4*)&Bc[o]     = *(float4*)&Bb[0];
    *(float4*)&Bc[o + 4] = *(float4*)&Bb[4];
}

// pass 2: sequential over chunks; AcH0 doubles as h0 output (read-before-write)
__global__ __launch_bounds__(256) void scan_pass2(float* __restrict__ AcH0,
                                                  const float* __restrict__ Bc) {
    int idx = blockIdx.x * 256 + threadIdx.x;   // b*D + d, 16384 total
    int b = idx >> 10, d = idx & (D_DIM - 1);
    float h = 0.f;
#pragma unroll 8
    for (int ch = 0; ch < NCH; ++ch) {
        size_t k = ((size_t)(b * NCH + ch) << 10) + d;
        float a = AcH0[k];
        float bv = Bc[k];
        AcH0[k] = h;
        h = fmaf(a, h, bv);
    }
}

// ---------------- fused scan pass 3 + LayerNorm (1 wave, 16 dims/lane) ----------------
__global__ __launch_bounds__(64) void scan_ln(const _Float16* __restrict__ u,
                                              const _Float16* __restrict__ cd,
                                              const float* __restrict__ h0,
                                              const float* __restrict__ gamma,
                                              const float* __restrict__ beta,
                                              float* __restrict__ outp) {
    int bc = blockIdx.x;                // b*NCH + ch
    int b = bc >> 7, ch = bc & (NCH - 1);
    int lane = threadIdx.x;             // 0..63
    int d0 = lane * 16;
    size_t base = ((size_t)b * T_DIM + (size_t)ch * CHUNK) * D_DIM + d0;

    float g[16], be[16], h[16];
#pragma unroll
    for (int j = 0; j < 16; j += 4) {
        *(float4*)&g[j]  = *(const float4*)&gamma[d0 + j];
        *(float4*)&be[j] = *(const float4*)&beta[d0 + j];
    }
    size_t o = (size_t)bc * D_DIM + d0;
#pragma unroll
    for (int j = 0; j < 16; j += 4) *(float4*)&h[j] = *(const float4*)&h0[o + j];

    for (int t = 0; t < CHUNK; ++t) {
        size_t row = base + (size_t)t * D_DIM;
        half8 ua = *(const half8*)&u[row];
        half8 ub = *(const half8*)&u[row + 8];
        half8 ca = *(const half8*)&cd[row];
        half8 cb = *(const half8*)&cd[row + 8];
        float s = 0.f, q = 0.f;
#pragma unroll
        for (int j = 0; j < 8; ++j) {
            float ut = (float)ua[j], ct = (float)ca[j];
            h[j] = fmaf(ut, h[j] - ct, ct);
            s += h[j]; q += h[j] * h[j];
        }
#pragma unroll
        for (int j = 0; j < 8; ++j) {
            float ut = (float)ub[j], ct = (float)cb[j];
            h[8 + j] = fmaf(ut, h[8 + j] - ct, ct);
            s += h[8 + j]; q += h[8 + j] * h[8 + j];
        }
#pragma unroll
        for (int off = 32; off > 0; off >>= 1) {
            s += __shfl_xor(s, off);
            q += __shfl_xor(q, off);
        }
        float mu = s * (1.f / D_DIM);
        float var = q * (1.f / D_DIM) - mu * mu;
        float rs = rsqrtf(var + LN_EPS);
        float o16[16];
#pragma unroll
        for (int j = 0; j < 16; ++j) o16[j] = (h[j] - mu) * rs * g[j] + be[j];
#pragma unroll
        for (int j = 0; j < 16; j += 4) *(float4*)&outp[row + j] = *(float4*)&o16[j];
    }
}

extern "C" void kernel_launch(void* const* d_in, const int* in_sizes, int n_in,
                              void* d_out, int out_size, void* d_ws, size_t ws_size,
                              hipStream_t stream) {
    const float* x       = (const float*)d_in[0];
    const float* W_in    = (const float*)d_in[1];
    const float* W_state = (const float*)d_in[2];
    const float* gamma   = (const float*)d_in[3];
    const float* beta    = (const float*)d_in[4];
    float* out = (float*)d_out;

    char* w = (char*)d_ws;
    size_t off = 0;
    auto carve = [&](size_t bytes) {
        void* p = w + off;
        off += (bytes + 255) & ~(size_t)255;
        return p;
    };
    _Float16* xh   = (_Float16*)carve((size_t)M_TOT * K_DIM * 2);           // 64 MiB
    _Float16* Wall = (_Float16*)carve((size_t)2 * D_DIM * K_DIM * 2);       // 4 MiB (W_g ; W_comb)
    _Float16* uarr = (_Float16*)carve((size_t)M_TOT * D_DIM * 2);           // 64 MiB
    _Float16* cand = (_Float16*)carve((size_t)M_TOT * D_DIM * 2);           // 64 MiB
    char* scratch  = (char*)carve((size_t)16 * 1024 * 1024);                // 16 MiB shared region
    _Float16* wvxT = (_Float16*)scratch;                                    // 2 MiB (early)
    _Float16* wst  = (_Float16*)(scratch + 2 * 1024 * 1024);                // 2 MiB (early)
    float* Ac = (float*)scratch;                                            // 8 MiB (late, also h0)
    float* Bc = (float*)(scratch + 8 * 1024 * 1024);                        // 8 MiB (late)

    // 1. casts
    cvt_f32_f16<<<2048, 256, 0, stream>>>(x, xh, M_TOT * K_DIM / 8);
    cvt_f32_f16<<<512, 256, 0, stream>>>(W_in, Wall, D_DIM * K_DIM / 8);
    transpose_cvt<<<dim3(32, 32), dim3(32, 8), 0, stream>>>(W_in + (size_t)D_DIM * K_DIM, wvxT);
    cvt_f32_f16<<<512, 256, 0, stream>>>(W_state, wst, D_DIM * K_DIM / 8);

    // 2. W_comb = W_state @ W_vx -> Wall[1024:2048]
    gemm256<<<16, 512, 0, stream>>>(wst, wvxT, 4, D_DIM, K_DIM,
                                    Wall + (size_t)D_DIM * K_DIM, nullptr, 0);

    // 3. fused projection: [u | cand] = x @ Wall^T  (sigmoid on u half)
    gemm256<<<(M_TOT / 256) * (2 * D_DIM / 256), 512, 0, stream>>>(
        xh, Wall, M_TOT / 256, 2 * D_DIM, K_DIM, uarr, cand, 1);

    // 4. chunked affine scan + fused LN
    scan_pass1<<<(B_DIM * NCH * 128) / 256, 256, 0, stream>>>(uarr, cand, Ac, Bc);
    scan_pass2<<<(B_DIM * D_DIM) / 256, 256, 0, stream>>>(Ac, Bc);
    scan_ln<<<B_DIM * NCH, 64, 0, stream>>>(uarr, cand, Ac, gamma, beta, out);
}

// Round 8
// 327.327 us; speedup vs baseline: 1.1051x; 1.0874x over previous
//
#include <hip/hip_runtime.h>

// ---- problem constants ----
#define D_DIM 1024
#define B_DIM 16
#define T_DIM 2048
#define M_TOT (B_DIM * T_DIM)   // 32768 rows
#define K_DIM 1024
#define LN_EPS 1e-5f
#define CHUNK 16
#define NCH (T_DIM / CHUNK)     // 128 chunks

typedef _Float16 half8 __attribute__((ext_vector_type(8)));
typedef _Float16 half4v __attribute__((ext_vector_type(4)));
typedef float f32x4 __attribute__((ext_vector_type(4)));

// ---------------- fp32 -> fp16 conversion, 8 elems/thread ----------------
__global__ __launch_bounds__(256) void cvt_f32_f16(const float* __restrict__ in,
                                                   _Float16* __restrict__ out, int n8) {
    int i = blockIdx.x * blockDim.x + threadIdx.x;
    int stride = gridDim.x * blockDim.x;
    for (; i < n8; i += stride) {
        const float4* p = (const float4*)in + 2 * (size_t)i;
        float4 a = p[0], b = p[1];
        half8 h;
        h[0] = (_Float16)a.x; h[1] = (_Float16)a.y; h[2] = (_Float16)a.z; h[3] = (_Float16)a.w;
        h[4] = (_Float16)b.x; h[5] = (_Float16)b.y; h[6] = (_Float16)b.z; h[7] = (_Float16)b.w;
        ((half8*)out)[i] = h;
    }
}

// ---------------- fp32 [1024][1024] -> fp16 transpose (for W_vx^T) ----------------
__global__ __launch_bounds__(256) void transpose_cvt(const float* __restrict__ in,
                                                     _Float16* __restrict__ out) {
    __shared__ _Float16 t[32][33];
    int bx = blockIdx.x * 32, by = blockIdx.y * 32;
    int tx = threadIdx.x, ty = threadIdx.y;   // (32, 8)
#pragma unroll
    for (int j = 0; j < 4; ++j)
        t[ty + 8 * j][tx] = (_Float16)in[(size_t)(by + ty + 8 * j) * 1024 + bx + tx];
    __syncthreads();
#pragma unroll
    for (int j = 0; j < 4; ++j)
        out[(size_t)(bx + ty + 8 * j) * 1024 + by + tx] = t[tx][ty + 8 * j];
}

// ---------------- async global->LDS helper ----------------
__device__ __forceinline__ void gl_lds16(const _Float16* g, _Float16* l) {
    __builtin_amdgcn_global_load_lds(
        (const __attribute__((address_space(1))) unsigned int*)g,
        (__attribute__((address_space(3))) unsigned int*)l,
        16, 0, 0);
}

// ========== 256x256 triple-buffered BK=32 fp16 MFMA GEMM (C = A * B^T) ==========
// Fine phases (r4) + deep slack (r7), combined:
//  - 3 LDS buffers (96 KiB); tile t+2 staged during tile t (A@ph0, B@ph1)
//    -> every load has 3-4 phases (>HBM latency) before its vmcnt.
//  - 2 phases per tile: {8 or 4 ds_read_b128 ; 1 stage ; barrier ; 16 MFMA ; barrier}
//  - vmcnt(4) once per tile at ph1 (ledger: 8 outstanding -> drain 4 oldest = tile t+1).
//  - unroll-3 K-loop with compile-time buffer index -> ds_read literal offsets.

// Stage a full 256x32 fp16 tile (16 KiB, 1024 16B-chunks) = 2 gl_lds / thread.
// Linear LDS dest + inverse-XOR'd global source chunk (both-sides swizzle).
__device__ __forceinline__ void stage32(const _Float16* __restrict__ G, int ld,
                                        int row0, int kt,
                                        _Float16* lds0, int wid, int lane) {
#pragma unroll
    for (int call = 0; call < 2; ++call) {
        int c0 = call * 512 + wid * 64;     // wave-uniform chunk base
        int c  = c0 + lane;                 // chunk 0..1023
        int rl = c >> 2;                    // row 0..255 (4 chunks/row)
        int cc = c & 3;
        int src = cc ^ ((rl >> 1) & 3);     // swizzled source chunk
        gl_lds16(G + (size_t)(row0 + rl) * ld + kt + src * 8,
                 lds0 + (size_t)c0 * 8);
    }
}

// Fragment read with matching XOR: conflict-free (0 conflicts measured r7).
__device__ __forceinline__ half8 frag32(const _Float16* base, int row, int kq) {
    int cc = kq ^ ((row >> 1) & 3);
    return *(const half8*)(base + (size_t)row * 32 + cc * 8);
}

template <int BUF>
__device__ __forceinline__ void gstep(const _Float16* __restrict__ A,
                                      const _Float16* __restrict__ Bm,
                                      int K, int m0, int n0, int t, int nkt,
                                      int wid, int lane, int wr, int wc, int r, int kq,
                                      _Float16 (&As)[3][256][32],
                                      _Float16 (&Bs)[3][256][32],
                                      f32x4 (&acc)[8][4]) {
    constexpr int NB = (BUF + 2) % 3;
    const int kt2 = (t + 2) << 5;
    half8 rb[4], ra0[4], ra1[4];

    // ---- phase 0: read rb + ra0 ; stage A(t+2) ; barrier ; MFMA acc[0..3] ----
#pragma unroll
    for (int ni = 0; ni < 4; ni++) rb[ni]  = frag32(&Bs[BUF][0][0], wc * 64 + ni * 16 + r, kq);
#pragma unroll
    for (int mi = 0; mi < 4; mi++) ra0[mi] = frag32(&As[BUF][0][0], wr * 128 + mi * 16 + r, kq);
    if (t + 2 < nkt) stage32(A, K, m0, kt2, &As[NB][0][0], wid, lane);
    __builtin_amdgcn_s_barrier();
    __builtin_amdgcn_s_setprio(1);
#pragma unroll
    for (int mi = 0; mi < 4; mi++)
#pragma unroll
        for (int ni = 0; ni < 4; ni++)
            acc[mi][ni] = __builtin_amdgcn_mfma_f32_16x16x32_f16(ra0[mi], rb[ni], acc[mi][ni], 0, 0, 0);
    __builtin_amdgcn_s_setprio(0);
    __builtin_amdgcn_s_barrier();

    // ---- phase 1: read ra1 ; stage B(t+2) ; vmcnt(4) ; barrier ; MFMA acc[4..7] ----
#pragma unroll
    for (int mi = 0; mi < 4; mi++) ra1[mi] = frag32(&As[BUF][0][0], wr * 128 + 64 + mi * 16 + r, kq);
    if (t + 2 < nkt) stage32(Bm, K, n0, kt2, &Bs[NB][0][0], wid, lane);
    {
        int rem = nkt - 1 - t;
        if (rem >= 2)      asm volatile("s_waitcnt vmcnt(4)" ::: "memory");  // t+1 landed
        else if (rem == 1) asm volatile("s_waitcnt vmcnt(0)" ::: "memory");
    }
    __builtin_amdgcn_s_barrier();                  // all waves: tile t+1 visible
    __builtin_amdgcn_s_setprio(1);
#pragma unroll
    for (int mi = 0; mi < 4; mi++)
#pragma unroll
        for (int ni = 0; ni < 4; ni++)
            acc[4 + mi][ni] = __builtin_amdgcn_mfma_f32_16x16x32_f16(ra1[mi], rb[ni], acc[4 + mi][ni], 0, 0, 0);
    __builtin_amdgcn_s_setprio(0);
    __builtin_amdgcn_s_barrier();
}

// mode 1 only: n < D -> out0 = sigmoid(acc) ; n >= D -> out1 = acc  (both fp16)
__global__ __launch_bounds__(512, 2) void gemm256(const _Float16* __restrict__ A,
                                                  const _Float16* __restrict__ Bm,
                                                  int Mtiles, int N, int K,
                                                  _Float16* __restrict__ out0,
                                                  _Float16* __restrict__ out1,
                                                  int mode) {
    __shared__ _Float16 As[3][256][32];   // 48 KiB
    __shared__ _Float16 Bs[3][256][32];   // 48 KiB

    int bid = blockIdx.x;
    int mt, nt;
    if (Mtiles == 128) {
        // 2-D XCD supertile: each XCD owns 16 mt x 8 nt (shares A + B panels)
        int xcd = bid & 7;
        mt = xcd * 16 + ((bid >> 3) & 15);
        nt = bid >> 7;
    } else {
        int cpx = gridDim.x >> 3;
        int lin = (bid & 7) * cpx + (bid >> 3);
        nt = lin / Mtiles; mt = lin % Mtiles;
    }
    int m0 = mt * 256, n0 = nt * 256;

    int tid = threadIdx.x, wid = tid >> 6, lane = tid & 63;
    int wr = wid >> 2, wc = wid & 3;         // 2 x 4 wave grid, per-wave 128x64
    int r = lane & 15, kq = lane >> 4;

    f32x4 acc[8][4];
#pragma unroll
    for (int i = 0; i < 8; i++)
#pragma unroll
        for (int j = 0; j < 4; j++) acc[i][j] = (f32x4)0.f;

    const int nkt = K >> 5;                  // 32 K-tiles of BK=32

    // ---- prologue: stage tiles 0,1 (8 loads/thread); wait tile0; barrier ----
    stage32(A,  K, m0, 0,  &As[0][0][0], wid, lane);
    stage32(Bm, K, n0, 0,  &Bs[0][0][0], wid, lane);
    stage32(A,  K, m0, 32, &As[1][0][0], wid, lane);
    stage32(Bm, K, n0, 32, &Bs[1][0][0], wid, lane);
    asm volatile("s_waitcnt vmcnt(4)" ::: "memory");   // own tile-0 loads landed
    __builtin_amdgcn_s_barrier();

    for (int t0 = 0; t0 < nkt; t0 += 3) {
        gstep<0>(A, Bm, K, m0, n0, t0,     nkt, wid, lane, wr, wc, r, kq, As, Bs, acc);
        if (t0 + 1 < nkt)
            gstep<1>(A, Bm, K, m0, n0, t0 + 1, nkt, wid, lane, wr, wc, r, kq, As, Bs, acc);
        if (t0 + 2 < nkt)
            gstep<2>(A, Bm, K, m0, n0, t0 + 2, nkt, wid, lane, wr, wc, r, kq, As, Bs, acc);
    }

    // ---- epilogue: C/D layout col = lane&15, row = (lane>>4)*4 + q ----
    int rr = kq * 4;
#pragma unroll
    for (int mi = 0; mi < 8; mi++) {
        int mbase = m0 + wr * 128 + mi * 16 + rr;
#pragma unroll
        for (int ni = 0; ni < 4; ni++) {
            int n = n0 + wc * 64 + ni * 16 + r;
#pragma unroll
            for (int q = 0; q < 4; q++) {
                float v = acc[mi][ni][q];
                size_t m = (size_t)(mbase + q);
                if (mode == 1) {
                    if (n < D_DIM)
                        out0[m * D_DIM + n] = (_Float16)(1.f / (1.f + __expf(-v)));
                    else
                        out1[m * D_DIM + (n - D_DIM)] = (_Float16)v;
                } else {
                    out0[m * (size_t)N + n] = (_Float16)v;
                }
            }
        }
    }
}

// ========== split-K W_comb GEMM (128x128 tile, r2-validated structure) ==========
// part[sl][m][n] = sum_{k in slice sl} Wst[m][k] * WvxT[n][k]   (fp32 partials)
__global__ __launch_bounds__(256) void wcomb_splitk(const _Float16* __restrict__ A,
                                                    const _Float16* __restrict__ Bm,
                                                    float* __restrict__ part) {
    __shared__ _Float16 As[128 * 32];
    __shared__ _Float16 Bs[128 * 32];
    int bid = blockIdx.x;                 // mt + 8*nt + 64*slice
    int mt = bid & 7, nt = (bid >> 3) & 7, sl = bid >> 6;
    int m0 = mt * 128, n0 = nt * 128, kbeg = sl * 256;
    int tid = threadIdx.x, wid = tid >> 6, lane = tid & 63;
    int wr = wid >> 1, wc = wid & 1;

    f32x4 acc[4][4];
#pragma unroll
    for (int i = 0; i < 4; i++)
#pragma unroll
        for (int j = 0; j < 4; j++) acc[i][j] = (f32x4)0.f;

    int r = lane & 15, kq = lane >> 4;

    for (int kt = kbeg; kt < kbeg + 256; kt += 32) {
        __syncthreads();
#pragma unroll
        for (int j = 0; j < 2; ++j) {
            int f = j * 256 + tid;
            int row = f >> 2, kc = f & 3;
            gl_lds16(A + (size_t)(m0 + row) * 1024 + kt + kc * 8, As + (size_t)(j * 256 + wid * 64) * 8);
            gl_lds16(Bm + (size_t)(n0 + row) * 1024 + kt + kc * 8, Bs + (size_t)(j * 256 + wid * 64) * 8);
        }
        __syncthreads();
        half8 af[4], bf[4];
#pragma unroll
        for (int mi = 0; mi < 4; mi++) af[mi] = *(const half8*)&As[(wr * 64 + mi * 16 + r) * 32 + kq * 8];
#pragma unroll
        for (int ni = 0; ni < 4; ni++) bf[ni] = *(const half8*)&Bs[(wc * 64 + ni * 16 + r) * 32 + kq * 8];
#pragma unroll
        for (int mi = 0; mi < 4; mi++)
#pragma unroll
            for (int ni = 0; ni < 4; ni++)
                acc[mi][ni] = __builtin_amdgcn_mfma_f32_16x16x32_f16(af[mi], bf[ni], acc[mi][ni], 0, 0, 0);
    }

    int rr = kq * 4;
    float* pb = part + (size_t)sl * 1048576;
#pragma unroll
    for (int mi = 0; mi < 4; mi++) {
        int mbase = m0 + wr * 64 + mi * 16 + rr;
#pragma unroll
        for (int ni = 0; ni < 4; ni++) {
            int n = n0 + wc * 64 + ni * 16 + r;
#pragma unroll
            for (int q = 0; q < 4; q++)
                pb[(size_t)(mbase + q) * 1024 + n] = acc[mi][ni][q];
        }
    }
}

__global__ __launch_bounds__(256) void wcomb_combine(const float* __restrict__ part,
                                                     _Float16* __restrict__ out) {
    int i = blockIdx.x * 256 + threadIdx.x;   // 0..262143 (float4 units)
    float4 s0 = ((const float4*)part)[i];
    float4 s1 = ((const float4*)(part + 1048576))[i];
    float4 s2 = ((const float4*)(part + 2097152))[i];
    float4 s3 = ((const float4*)(part + 3145728))[i];
    half4v o;
    o[0] = (_Float16)(s0.x + s1.x + s2.x + s3.x);
    o[1] = (_Float16)(s0.y + s1.y + s2.y + s3.y);
    o[2] = (_Float16)(s0.z + s1.z + s2.z + s3.z);
    o[3] = (_Float16)(s0.w + s1.w + s2.w + s3.w);
    ((half4v*)out)[i] = o;
}

// ---------------- chunked affine scan, pass 1 (CHUNK=16) ----------------
__global__ __launch_bounds__(256) void scan_pass1(const _Float16* __restrict__ u,
                                                  const _Float16* __restrict__ cd,
                                                  float* __restrict__ Ac, float* __restrict__ Bc) {
    int idx = blockIdx.x * 256 + threadIdx.x;   // (b*NCH + ch)*128 + dg
    int dg = idx & 127, bc = idx >> 7;
    int b = bc >> 7, ch = bc & (NCH - 1);
    int d0 = dg * 8;
    size_t base = ((size_t)b * T_DIM + (size_t)ch * CHUNK) * D_DIM + d0;
    float Aa[8], Bb[8];
#pragma unroll
    for (int j = 0; j < 8; ++j) { Aa[j] = 1.f; Bb[j] = 0.f; }
#pragma unroll
    for (int t = 0; t < CHUNK; ++t) {
        half8 u8 = *(const half8*)&u[base + (size_t)t * D_DIM];
        half8 c8 = *(const half8*)&cd[base + (size_t)t * D_DIM];
#pragma unroll
        for (int j = 0; j < 8; ++j) {
            float ut = (float)u8[j], ct = (float)c8[j];
            Aa[j] *= ut;
            Bb[j] = fmaf(ut, Bb[j], (1.f - ut) * ct);
        }
    }
    size_t o = (size_t)bc * D_DIM + d0;
    *(float4*)&Ac[o]     = *(float4*)&Aa[0];
    *(float4*)&Ac[o + 4] = *(float4*)&Aa[4];
    *(float4*)&Bc[o]     = *(float4*)&Bb[0];
    *(float4*)&Bc[o + 4] = *(float4*)&Bb[4];
}

// pass 2: sequential over chunks; AcH0 doubles as h0 output (read-before-write)
__global__ __launch_bounds__(256) void scan_pass2(float* __restrict__ AcH0,
                                                  const float* __restrict__ Bc) {
    int idx = blockIdx.x * 256 + threadIdx.x;   // b*D + d, 16384 total
    int b = idx >> 10, d = idx & (D_DIM - 1);
    float h = 0.f;
#pragma unroll 8
    for (int ch = 0; ch < NCH; ++ch) {
        size_t k = ((size_t)(b * NCH + ch) << 10) + d;
        float a = AcH0[k];
        float bv = Bc[k];
        AcH0[k] = h;
        h = fmaf(a, h, bv);
    }
}

// ---------------- fused scan pass 3 + LayerNorm (1 wave, 16 dims/lane) ----------------
__global__ __launch_bounds__(64) void scan_ln(const _Float16* __restrict__ u,
                                              const _Float16* __restrict__ cd,
                                              const float* __restrict__ h0,
                                              const float* __restrict__ gamma,
                                              const float* __restrict__ beta,
                                              float* __restrict__ outp) {
    int bc = blockIdx.x;                // b*NCH + ch
    int b = bc >> 7, ch = bc & (NCH - 1);
    int lane = threadIdx.x;             // 0..63
    int d0 = lane * 16;
    size_t base = ((size_t)b * T_DIM + (size_t)ch * CHUNK) * D_DIM + d0;

    float g[16], be[16], h[16];
#pragma unroll
    for (int j = 0; j < 16; j += 4) {
        *(float4*)&g[j]  = *(const float4*)&gamma[d0 + j];
        *(float4*)&be[j] = *(const float4*)&beta[d0 + j];
    }
    size_t o = (size_t)bc * D_DIM + d0;
#pragma unroll
    for (int j = 0; j < 16; j += 4) *(float4*)&h[j] = *(const float4*)&h0[o + j];

    for (int t = 0; t < CHUNK; ++t) {
        size_t row = base + (size_t)t * D_DIM;
        half8 ua = *(const half8*)&u[row];
        half8 ub = *(const half8*)&u[row + 8];
        half8 ca = *(const half8*)&cd[row];
        half8 cb = *(const half8*)&cd[row + 8];
        float s = 0.f, q = 0.f;
#pragma unroll
        for (int j = 0; j < 8; ++j) {
            float ut = (float)ua[j], ct = (float)ca[j];
            h[j] = fmaf(ut, h[j] - ct, ct);
            s += h[j]; q += h[j] * h[j];
        }
#pragma unroll
        for (int j = 0; j < 8; ++j) {
            float ut = (float)ub[j], ct = (float)cb[j];
            h[8 + j] = fmaf(ut, h[8 + j] - ct, ct);
            s += h[8 + j]; q += h[8 + j] * h[8 + j];
        }
#pragma unroll
        for (int off = 32; off > 0; off >>= 1) {
            s += __shfl_xor(s, off);
            q += __shfl_xor(q, off);
        }
        float mu = s * (1.f / D_DIM);
        float var = q * (1.f / D_DIM) - mu * mu;
        float rs = rsqrtf(var + LN_EPS);
        float o16[16];
#pragma unroll
        for (int j = 0; j < 16; ++j) o16[j] = (h[j] - mu) * rs * g[j] + be[j];
#pragma unroll
        for (int j = 0; j < 16; j += 4) *(float4*)&outp[row + j] = *(float4*)&o16[j];
    }
}

extern "C" void kernel_launch(void* const* d_in, const int* in_sizes, int n_in,
                              void* d_out, int out_size, void* d_ws, size_t ws_size,
                              hipStream_t stream) {
    const float* x       = (const float*)d_in[0];
    const float* W_in    = (const float*)d_in[1];
    const float* W_state = (const float*)d_in[2];
    const float* gamma   = (const float*)d_in[3];
    const float* beta    = (const float*)d_in[4];
    float* out = (float*)d_out;

    char* w = (char*)d_ws;
    size_t off = 0;
    auto carve = [&](size_t bytes) {
        void* p = w + off;
        off += (bytes + 255) & ~(size_t)255;
        return p;
    };
    _Float16* xh   = (_Float16*)carve((size_t)M_TOT * K_DIM * 2);           // 64 MiB
    _Float16* Wall = (_Float16*)carve((size_t)2 * D_DIM * K_DIM * 2);       // 4 MiB (W_g ; W_comb)
    _Float16* uarr = (_Float16*)carve((size_t)M_TOT * D_DIM * 2);           // 64 MiB
    _Float16* cand = (_Float16*)carve((size_t)M_TOT * D_DIM * 2);           // 64 MiB
    char* scratch  = (char*)carve((size_t)16 * 1024 * 1024);                // 16 MiB shared region
    _Float16* wvxT = (_Float16*)scratch;                                    // 2 MiB (early)
    _Float16* wst  = (_Float16*)(scratch + 2 * 1024 * 1024);                // 2 MiB (early)
    float* Ac = (float*)scratch;                                            // 8 MiB (late, also h0)
    float* Bc = (float*)(scratch + 8 * 1024 * 1024);                        // 8 MiB (late)
    float* wpart = (float*)cand;   // 16 MiB fp32 partials; cand dead until main GEMM

    // 1. casts
    cvt_f32_f16<<<2048, 256, 0, stream>>>(x, xh, M_TOT * K_DIM / 8);
    cvt_f32_f16<<<512, 256, 0, stream>>>(W_in, Wall, D_DIM * K_DIM / 8);
    transpose_cvt<<<dim3(32, 32), dim3(32, 8), 0, stream>>>(W_in + (size_t)D_DIM * K_DIM, wvxT);
    cvt_f32_f16<<<512, 256, 0, stream>>>(W_state, wst, D_DIM * K_DIM / 8);

    // 2. W_comb = W_state @ W_vx -> Wall[1024:2048]  (split-K x4, 256 blocks)
    wcomb_splitk<<<256, 256, 0, stream>>>(wst, wvxT, wpart);
    wcomb_combine<<<1024, 256, 0, stream>>>(wpart, Wall + (size_t)D_DIM * K_DIM);

    // 3. fused projection: [u | cand] = x @ Wall^T  (sigmoid on u half)
    gemm256<<<(M_TOT / 256) * (2 * D_DIM / 256), 512, 0, stream>>>(
        xh, Wall, M_TOT / 256, 2 * D_DIM, K_DIM, uarr, cand, 1);

    // 4. chunked affine scan + fused LN
    scan_pass1<<<(B_DIM * NCH * 128) / 256, 256, 0, stream>>>(uarr, cand, Ac, Bc);
    scan_pass2<<<(B_DIM * D_DIM) / 256, 256, 0, stream>>>(Ac, Bc);
    scan_ln<<<B_DIM * NCH, 64, 0, stream>>>(uarr, cand, Ac, gamma, beta, out);
}